// Round 1
// baseline (1299.789 us; speedup 1.0000x reference)
//
#include <hip/hip_runtime.h>
#include <hip/hip_bf16.h>
#include <math.h>

#define L_SEQ  2048
#define NBATCH 2
#define NTOK   4096      // NBATCH * L_SEQ
#define DMODEL 512
#define DINNER 1024
#define DTRANK 32
#define DSTATE 16

__device__ __forceinline__ float sigmoidf_(float x) {
    return 1.0f / (1.0f + __expf(-x));
}

// ---------------------------------------------------------------------------
// LayerNorm: one wave per row of 512, 4 rows per block
// ---------------------------------------------------------------------------
__global__ __launch_bounds__(256) void ln_k(const float* __restrict__ x,
                                            const float* __restrict__ g,
                                            const float* __restrict__ b,
                                            float* __restrict__ xn)
{
    const int w    = threadIdx.x >> 6;
    const int lane = threadIdx.x & 63;
    const int row  = (blockIdx.x << 2) + w;
    const float* xr = x + (size_t)row * DMODEL;

    float4 v0 = *(const float4*)(xr + lane * 8);
    float4 v1 = *(const float4*)(xr + lane * 8 + 4);

    float s = v0.x + v0.y + v0.z + v0.w + v1.x + v1.y + v1.z + v1.w;
    #pragma unroll
    for (int o = 1; o < 64; o <<= 1) s += __shfl_xor(s, o, 64);
    const float mu = s * (1.0f / DMODEL);

    float d0 = v0.x - mu, d1 = v0.y - mu, d2 = v0.z - mu, d3 = v0.w - mu;
    float d4 = v1.x - mu, d5 = v1.y - mu, d6 = v1.z - mu, d7 = v1.w - mu;
    float ss = d0*d0 + d1*d1 + d2*d2 + d3*d3 + d4*d4 + d5*d5 + d6*d6 + d7*d7;
    #pragma unroll
    for (int o = 1; o < 64; o <<= 1) ss += __shfl_xor(ss, o, 64);
    const float rs = rsqrtf(ss * (1.0f / DMODEL) + 1e-5f);

    float4 g0 = *(const float4*)(g + lane * 8);
    float4 g1 = *(const float4*)(g + lane * 8 + 4);
    float4 b0 = *(const float4*)(b + lane * 8);
    float4 b1 = *(const float4*)(b + lane * 8 + 4);

    float* outr = xn + (size_t)row * DMODEL;
    float4 o0, o1;
    o0.x = d0 * rs * g0.x + b0.x;  o0.y = d1 * rs * g0.y + b0.y;
    o0.z = d2 * rs * g0.z + b0.z;  o0.w = d3 * rs * g0.w + b0.w;
    o1.x = d4 * rs * g1.x + b1.x;  o1.y = d5 * rs * g1.y + b1.y;
    o1.z = d6 * rs * g1.z + b1.z;  o1.w = d7 * rs * g1.w + b1.w;
    *(float4*)(outr + lane * 8)     = o0;
    *(float4*)(outr + lane * 8 + 4) = o1;
}

// ---------------------------------------------------------------------------
// Generic fp32 tiled GEMM: C[M,N] = A[M,K] @ B[K,N] (+ epilogue)
// 64x64 tile, BK=16, 256 threads, 4x4 micro-tile. All dims multiples of tile.
// EPI: 0 = store, 1 = softplus(acc + bias), 2 = C += acc, 3 = acc+bias+resid
// ---------------------------------------------------------------------------
template<int EPI>
__global__ __launch_bounds__(256) void gemm_k(const float* __restrict__ A, int lda,
                                              const float* __restrict__ B, int ldb,
                                              float* __restrict__ C, int ldc,
                                              int K,
                                              const float* __restrict__ bias,
                                              const float* __restrict__ resid,
                                              int ldres)
{
    __shared__ float As[16][64];
    __shared__ float Bs[16][64];

    const int tid  = threadIdx.x;
    const int bm   = blockIdx.y << 6;
    const int bn   = blockIdx.x << 6;
    const int trow = (tid >> 4) << 2;   // 0..60
    const int tcol = (tid & 15) << 2;   // 0..60

    const int am  = tid >> 2;           // 0..63
    const int ak  = (tid & 3) << 2;     // 0,4,8,12
    const int bk  = tid >> 4;           // 0..15
    const int bnn = (tid & 15) << 2;    // 0..60

    float acc[4][4] = {};

    for (int k0 = 0; k0 < K; k0 += 16) {
        float4 av = *(const float4*)(A + (size_t)(bm + am) * lda + k0 + ak);
        float4 bv = *(const float4*)(B + (size_t)(k0 + bk) * ldb + bn + bnn);
        As[ak + 0][am] = av.x;
        As[ak + 1][am] = av.y;
        As[ak + 2][am] = av.z;
        As[ak + 3][am] = av.w;
        *(float4*)(&Bs[bk][bnn]) = bv;
        __syncthreads();
        #pragma unroll
        for (int kk = 0; kk < 16; ++kk) {
            float4 a4 = *(const float4*)(&As[kk][trow]);
            float4 b4 = *(const float4*)(&Bs[kk][tcol]);
            float ar[4] = {a4.x, a4.y, a4.z, a4.w};
            float br[4] = {b4.x, b4.y, b4.z, b4.w};
            #pragma unroll
            for (int i = 0; i < 4; ++i)
                #pragma unroll
                for (int j = 0; j < 4; ++j)
                    acc[i][j] = fmaf(ar[i], br[j], acc[i][j]);
        }
        __syncthreads();
    }

    #pragma unroll
    for (int i = 0; i < 4; ++i) {
        const int row = bm + trow + i;
        float* cp = C + (size_t)row * ldc + bn + tcol;
        float4 v;
        v.x = acc[i][0]; v.y = acc[i][1]; v.z = acc[i][2]; v.w = acc[i][3];
        if (EPI == 0) {
            *(float4*)cp = v;
        } else if (EPI == 1) {
            float r[4] = {v.x, v.y, v.z, v.w};
            #pragma unroll
            for (int j = 0; j < 4; ++j) {
                float t = r[j] + bias[bn + tcol + j];
                r[j] = (t > 20.0f) ? t : log1pf(__expf(t));
            }
            v.x = r[0]; v.y = r[1]; v.z = r[2]; v.w = r[3];
            *(float4*)cp = v;
        } else if (EPI == 2) {
            float4 c0 = *(const float4*)cp;
            v.x += c0.x; v.y += c0.y; v.z += c0.z; v.w += c0.w;
            *(float4*)cp = v;
        } else {
            const float* rp = resid + (size_t)row * ldres + bn + tcol;
            float4 rv = *(const float4*)rp;
            v.x += bias[bn + tcol + 0] + rv.x;
            v.y += bias[bn + tcol + 1] + rv.y;
            v.z += bias[bn + tcol + 2] + rv.z;
            v.w += bias[bn + tcol + 3] + rv.w;
            *(float4*)cp = v;
        }
    }
}

// ---------------------------------------------------------------------------
// Depthwise causal (rev=0) / anticausal (rev=1) conv, k=4, + bias + SiLU
// ---------------------------------------------------------------------------
__global__ __launch_bounds__(256) void conv_silu_k(const float* __restrict__ xin,
                                                   const float* __restrict__ w,
                                                   const float* __restrict__ cb,
                                                   float* __restrict__ xout,
                                                   int rev)
{
    const int gidx = blockIdx.x * 256 + threadIdx.x;  // over NTOK*DINNER
    const int d = gidx & (DINNER - 1);
    const int t = gidx >> 10;
    const int l = t & (L_SEQ - 1);
    const int base_bl = t - l;  // b * L_SEQ

    float acc = cb[d];
    const float w0 = w[d * 4 + 0], w1 = w[d * 4 + 1];
    const float w2 = w[d * 4 + 2], w3 = w[d * 4 + 3];

    if (!rev) {
        if (l >= 3) acc = fmaf(w0, xin[(size_t)(base_bl + l - 3) * DINNER + d], acc);
        if (l >= 2) acc = fmaf(w1, xin[(size_t)(base_bl + l - 2) * DINNER + d], acc);
        if (l >= 1) acc = fmaf(w2, xin[(size_t)(base_bl + l - 1) * DINNER + d], acc);
        acc = fmaf(w3, xin[(size_t)t * DINNER + d], acc);
    } else {
        acc = fmaf(w3, xin[(size_t)t * DINNER + d], acc);
        if (l + 1 < L_SEQ) acc = fmaf(w2, xin[(size_t)(base_bl + l + 1) * DINNER + d], acc);
        if (l + 2 < L_SEQ) acc = fmaf(w1, xin[(size_t)(base_bl + l + 2) * DINNER + d], acc);
        if (l + 3 < L_SEQ) acc = fmaf(w0, xin[(size_t)(base_bl + l + 3) * DINNER + d], acc);
    }
    xout[gidx] = acc * sigmoidf_(acc);
}

// ---------------------------------------------------------------------------
// Selective scan, both branches in one launch (256 blocks).
// Block = (b, 16 d-channels); thread = (d_local, n) chain; 16-lane n-reduce.
// Fuses  y = (sum_n h*C + xi*D) * silu(z).  Direction via reversed iteration.
// ---------------------------------------------------------------------------
__global__ __launch_bounds__(256) void scan_k(
    const float* __restrict__ dt0, const float* __restrict__ dt1,
    const float* __restrict__ xi0, const float* __restrict__ xi1,
    const float* __restrict__ z0,  const float* __restrict__ z1,
    const float* __restrict__ xd0, const float* __restrict__ xd1,
    float* __restrict__ y0,        float* __restrict__ y1,
    const float* __restrict__ Al0, const float* __restrict__ Al1,
    const float* __restrict__ D0,  const float* __restrict__ D1)
{
    const int br  = blockIdx.x >> 7;
    const int blk = blockIdx.x & 127;
    const int b   = blk >> 6;
    const int d0  = (blk & 63) << 4;

    const float* dt = br ? dt1 : dt0;
    const float* xi = br ? xi1 : xi0;
    const float* zz = br ? z1  : z0;
    const float* xd = br ? xd1 : xd0;
    float*       y  = br ? y1  : y0;
    const float* Al = br ? Al1 : Al0;
    const float* Dp = br ? D1  : D0;
    const int rev = br;

    const int tid = threadIdx.x;
    const int dl  = tid >> 4;    // 0..15
    const int n   = tid & 15;    // 0..15
    const int d   = d0 + dl;

    // A2 = -exp(A_log) * log2(e)  -> dA = exp2(dt * A2)
    const float A2 = -__expf(Al[d * DSTATE + n]) * 1.44269504f;
    const float Dd = Dp[d];

    __shared__ float s_dt[64][16];
    __shared__ float s_xi[64][16];
    __shared__ float s_z [64][16];
    __shared__ float s_bc[64][32];   // [:,0:16]=Bm, [:,16:32]=Cm
    __shared__ float s_y [64][16];

    const int lrow = tid >> 2;          // 0..63
    const int lcol = (tid & 3) << 2;    // 0,4,8,12
    const int bcol = (tid & 3) << 3;    // 0,8,16,24

    float h = 0.0f;
    const size_t baseTok = (size_t)b * L_SEQ;

    for (int c = 0; c < 32; ++c) {
        const int cc = rev ? 31 - c : c;
        const int l0 = cc << 6;
        const size_t rowTok = baseTok + l0 + lrow;

        *(float4*)(&s_dt[lrow][lcol])     = *(const float4*)(dt + rowTok * DINNER + d0 + lcol);
        *(float4*)(&s_xi[lrow][lcol])     = *(const float4*)(xi + rowTok * DINNER + d0 + lcol);
        *(float4*)(&s_z [lrow][lcol])     = *(const float4*)(zz + rowTok * DINNER + d0 + lcol);
        *(float4*)(&s_bc[lrow][bcol])     = *(const float4*)(xd + rowTok * 64 + 32 + bcol);
        *(float4*)(&s_bc[lrow][bcol + 4]) = *(const float4*)(xd + rowTok * 64 + 36 + bcol);
        __syncthreads();

        #pragma unroll 4
        for (int r = 0; r < 64; ++r) {
            const int rr = rev ? 63 - r : r;
            const float dtv = s_dt[rr][dl];
            const float xiv = s_xi[rr][dl];
            const float bv  = s_bc[rr][n];
            const float cv  = s_bc[rr][16 + n];
            const float dA  = exp2f(dtv * A2);
            h = fmaf(dA, h, dtv * bv * xiv);
            float p = h * cv;
            p += __shfl_xor(p, 1, 64);
            p += __shfl_xor(p, 2, 64);
            p += __shfl_xor(p, 4, 64);
            p += __shfl_xor(p, 8, 64);
            if (n == 0) {
                const float zv = s_z[rr][dl];
                s_y[rr][dl] = (p + xiv * Dd) * (zv * sigmoidf_(zv));
            }
        }
        __syncthreads();
        *(float4*)(y + rowTok * DINNER + d0 + lcol) = *(const float4*)(&s_y[lrow][lcol]);
        __syncthreads();
    }
}

// ---------------------------------------------------------------------------
extern "C" void kernel_launch(void* const* d_in, const int* in_sizes, int n_in,
                              void* d_out, int out_size, void* d_ws, size_t ws_size,
                              hipStream_t stream)
{
    const float* x      = (const float*)d_in[0];
    const float* ln_g   = (const float*)d_in[1];
    const float* ln_b   = (const float*)d_in[2];
    const float* proj_w = (const float*)d_in[3];
    const float* proj_b = (const float*)d_in[4];
    const float* p_in_w[2]   = {(const float*)d_in[5],  (const float*)d_in[14]};
    const float* p_conv_w[2] = {(const float*)d_in[6],  (const float*)d_in[15]};
    const float* p_conv_b[2] = {(const float*)d_in[7],  (const float*)d_in[16]};
    const float* p_xproj[2]  = {(const float*)d_in[8],  (const float*)d_in[17]};
    const float* p_dt_w[2]   = {(const float*)d_in[9],  (const float*)d_in[18]};
    const float* p_dt_b[2]   = {(const float*)d_in[10], (const float*)d_in[19]};
    const float* p_Alog[2]   = {(const float*)d_in[11], (const float*)d_in[20]};
    const float* p_D[2]      = {(const float*)d_in[12], (const float*)d_in[21]};
    const float* p_out_w[2]  = {(const float*)d_in[13], (const float*)d_in[22]};

    float* ws = (float*)d_ws;
    size_t o = 0;
    float* xn = ws;                o += (size_t)NTOK * DMODEL;
    float *xiraw[2], *zb[2], *xib[2], *xdb[2], *dtb[2];
    for (int br = 0; br < 2; ++br) {
        xiraw[br] = ws + o;  o += (size_t)NTOK * DINNER;   // reused as y after conv
        zb[br]    = ws + o;  o += (size_t)NTOK * DINNER;
        xib[br]   = ws + o;  o += (size_t)NTOK * DINNER;
        xdb[br]   = ws + o;  o += (size_t)NTOK * 64;
        dtb[br]   = ws + o;  o += (size_t)NTOK * DINNER;
    }
    float* fbsum = ws + o;         o += (size_t)NTOK * DMODEL;

    const dim3 blk(256);

    // xn = LayerNorm(x)
    ln_k<<<NTOK / 4, blk, 0, stream>>>(x, ln_g, ln_b, xn);

    for (int br = 0; br < 2; ++br) {
        // xi_raw = xn @ in_w[:, :1024] ; z = xn @ in_w[:, 1024:]
        gemm_k<0><<<dim3(DINNER / 64, NTOK / 64), blk, 0, stream>>>(
            xn, DMODEL, p_in_w[br], 2 * DINNER, xiraw[br], DINNER, DMODEL,
            nullptr, nullptr, 0);
        gemm_k<0><<<dim3(DINNER / 64, NTOK / 64), blk, 0, stream>>>(
            xn, DMODEL, p_in_w[br] + DINNER, 2 * DINNER, zb[br], DINNER, DMODEL,
            nullptr, nullptr, 0);
        // xi = silu(conv(xi_raw) + conv_b)   (anticausal for backward branch)
        conv_silu_k<<<NTOK * DINNER / 256, blk, 0, stream>>>(
            xiraw[br], p_conv_w[br], p_conv_b[br], xib[br], br);
        // xdbl = xi @ xproj_w   (N=64: [0:32]=dt_in, [32:48]=B, [48:64]=C)
        gemm_k<0><<<dim3(1, NTOK / 64), blk, 0, stream>>>(
            xib[br], DINNER, p_xproj[br], 64, xdb[br], 64, DINNER,
            nullptr, nullptr, 0);
        // dt = softplus(xdbl[:, :32] @ dt_w + dt_b)
        gemm_k<1><<<dim3(DINNER / 64, NTOK / 64), blk, 0, stream>>>(
            xdb[br], 64, p_dt_w[br], DINNER, dtb[br], DINNER, DTRANK,
            p_dt_b[br], nullptr, 0);
    }

    // both branches' scans concurrently; writes gated y into xiraw buffers
    scan_k<<<256, blk, 0, stream>>>(dtb[0], dtb[1], xib[0], xib[1],
                                    zb[0], zb[1], xdb[0], xdb[1],
                                    xiraw[0], xiraw[1],
                                    p_Alog[0], p_Alog[1], p_D[0], p_D[1]);

    // fbsum = y_f @ out_w_f ; fbsum += y_b @ out_w_b
    gemm_k<0><<<dim3(DMODEL / 64, NTOK / 64), blk, 0, stream>>>(
        xiraw[0], DINNER, p_out_w[0], DMODEL, fbsum, DMODEL, DINNER,
        nullptr, nullptr, 0);
    gemm_k<2><<<dim3(DMODEL / 64, NTOK / 64), blk, 0, stream>>>(
        xiraw[1], DINNER, p_out_w[1], DMODEL, fbsum, DMODEL, DINNER,
        nullptr, nullptr, 0);

    // out = fbsum @ proj_w + proj_b + x
    gemm_k<3><<<dim3(DMODEL / 64, NTOK / 64), blk, 0, stream>>>(
        fbsum, DMODEL, proj_w, DMODEL, (float*)d_out, DMODEL, DMODEL,
        proj_b, x, DMODEL);
}

// Round 2
// 939.792 us; speedup vs baseline: 1.3831x; 1.3831x over previous
//
#include <hip/hip_runtime.h>
#include <hip/hip_bf16.h>
#include <math.h>

#define L_SEQ  2048
#define NBATCH 2
#define NTOK   4096      // NBATCH * L_SEQ
#define DMODEL 512
#define DINNER 1024
#define DTRANK 32
#define DSTATE 16
#define NCHUNK 32
#define CHUNK  64        // L_SEQ / NCHUNK

__device__ __forceinline__ float sigmoidf_(float x) {
    return 1.0f / (1.0f + __expf(-x));
}

// ---------------------------------------------------------------------------
// LayerNorm: one wave per row of 512, 4 rows per block
// ---------------------------------------------------------------------------
__global__ __launch_bounds__(256) void ln_k(const float* __restrict__ x,
                                            const float* __restrict__ g,
                                            const float* __restrict__ b,
                                            float* __restrict__ xn)
{
    const int w    = threadIdx.x >> 6;
    const int lane = threadIdx.x & 63;
    const int row  = (blockIdx.x << 2) + w;
    const float* xr = x + (size_t)row * DMODEL;

    float4 v0 = *(const float4*)(xr + lane * 8);
    float4 v1 = *(const float4*)(xr + lane * 8 + 4);

    float s = v0.x + v0.y + v0.z + v0.w + v1.x + v1.y + v1.z + v1.w;
    #pragma unroll
    for (int o = 1; o < 64; o <<= 1) s += __shfl_xor(s, o, 64);
    const float mu = s * (1.0f / DMODEL);

    float d0 = v0.x - mu, d1 = v0.y - mu, d2 = v0.z - mu, d3 = v0.w - mu;
    float d4 = v1.x - mu, d5 = v1.y - mu, d6 = v1.z - mu, d7 = v1.w - mu;
    float ss = d0*d0 + d1*d1 + d2*d2 + d3*d3 + d4*d4 + d5*d5 + d6*d6 + d7*d7;
    #pragma unroll
    for (int o = 1; o < 64; o <<= 1) ss += __shfl_xor(ss, o, 64);
    const float rs = rsqrtf(ss * (1.0f / DMODEL) + 1e-5f);

    float4 g0 = *(const float4*)(g + lane * 8);
    float4 g1 = *(const float4*)(g + lane * 8 + 4);
    float4 b0 = *(const float4*)(b + lane * 8);
    float4 b1 = *(const float4*)(b + lane * 8 + 4);

    float* outr = xn + (size_t)row * DMODEL;
    float4 o0, o1;
    o0.x = d0 * rs * g0.x + b0.x;  o0.y = d1 * rs * g0.y + b0.y;
    o0.z = d2 * rs * g0.z + b0.z;  o0.w = d3 * rs * g0.w + b0.w;
    o1.x = d4 * rs * g1.x + b1.x;  o1.y = d5 * rs * g1.y + b1.y;
    o1.z = d6 * rs * g1.z + b1.z;  o1.w = d7 * rs * g1.w + b1.w;
    *(float4*)(outr + lane * 8)     = o0;
    *(float4*)(outr + lane * 8 + 4) = o1;
}

// ---------------------------------------------------------------------------
// Generic fp32 tiled GEMM: C[M,N] = A[M,K] @ B[K,N] (+ epilogue)
// EPI: 0 = store, 1 = softplus(acc + bias), 2 = C += acc, 3 = acc+bias+resid
// ---------------------------------------------------------------------------
template<int EPI>
__global__ __launch_bounds__(256) void gemm_k(const float* __restrict__ A, int lda,
                                              const float* __restrict__ B, int ldb,
                                              float* __restrict__ C, int ldc,
                                              int K,
                                              const float* __restrict__ bias,
                                              const float* __restrict__ resid,
                                              int ldres)
{
    __shared__ float As[16][64];
    __shared__ float Bs[16][64];

    const int tid  = threadIdx.x;
    const int bm   = blockIdx.y << 6;
    const int bn   = blockIdx.x << 6;
    const int trow = (tid >> 4) << 2;
    const int tcol = (tid & 15) << 2;

    const int am  = tid >> 2;
    const int ak  = (tid & 3) << 2;
    const int bk  = tid >> 4;
    const int bnn = (tid & 15) << 2;

    float acc[4][4] = {};

    for (int k0 = 0; k0 < K; k0 += 16) {
        float4 av = *(const float4*)(A + (size_t)(bm + am) * lda + k0 + ak);
        float4 bv = *(const float4*)(B + (size_t)(k0 + bk) * ldb + bn + bnn);
        As[ak + 0][am] = av.x;
        As[ak + 1][am] = av.y;
        As[ak + 2][am] = av.z;
        As[ak + 3][am] = av.w;
        *(float4*)(&Bs[bk][bnn]) = bv;
        __syncthreads();
        #pragma unroll
        for (int kk = 0; kk < 16; ++kk) {
            float4 a4 = *(const float4*)(&As[kk][trow]);
            float4 b4 = *(const float4*)(&Bs[kk][tcol]);
            float ar[4] = {a4.x, a4.y, a4.z, a4.w};
            float br[4] = {b4.x, b4.y, b4.z, b4.w};
            #pragma unroll
            for (int i = 0; i < 4; ++i)
                #pragma unroll
                for (int j = 0; j < 4; ++j)
                    acc[i][j] = fmaf(ar[i], br[j], acc[i][j]);
        }
        __syncthreads();
    }

    #pragma unroll
    for (int i = 0; i < 4; ++i) {
        const int row = bm + trow + i;
        float* cp = C + (size_t)row * ldc + bn + tcol;
        float4 v;
        v.x = acc[i][0]; v.y = acc[i][1]; v.z = acc[i][2]; v.w = acc[i][3];
        if (EPI == 0) {
            *(float4*)cp = v;
        } else if (EPI == 1) {
            float r[4] = {v.x, v.y, v.z, v.w};
            #pragma unroll
            for (int j = 0; j < 4; ++j) {
                float t = r[j] + bias[bn + tcol + j];
                r[j] = (t > 20.0f) ? t : log1pf(__expf(t));
            }
            v.x = r[0]; v.y = r[1]; v.z = r[2]; v.w = r[3];
            *(float4*)cp = v;
        } else if (EPI == 2) {
            float4 c0 = *(const float4*)cp;
            v.x += c0.x; v.y += c0.y; v.z += c0.z; v.w += c0.w;
            *(float4*)cp = v;
        } else {
            const float* rp = resid + (size_t)row * ldres + bn + tcol;
            float4 rv = *(const float4*)rp;
            v.x += bias[bn + tcol + 0] + rv.x;
            v.y += bias[bn + tcol + 1] + rv.y;
            v.z += bias[bn + tcol + 2] + rv.z;
            v.w += bias[bn + tcol + 3] + rv.w;
            *(float4*)cp = v;
        }
    }
}

// ---------------------------------------------------------------------------
// Depthwise causal (rev=0) / anticausal (rev=1) conv, k=4, + bias + SiLU
// ---------------------------------------------------------------------------
__global__ __launch_bounds__(256) void conv_silu_k(const float* __restrict__ xin,
                                                   const float* __restrict__ w,
                                                   const float* __restrict__ cb,
                                                   float* __restrict__ xout,
                                                   int rev)
{
    const int gidx = blockIdx.x * 256 + threadIdx.x;
    const int d = gidx & (DINNER - 1);
    const int t = gidx >> 10;
    const int l = t & (L_SEQ - 1);
    const int base_bl = t - l;

    float acc = cb[d];
    const float w0 = w[d * 4 + 0], w1 = w[d * 4 + 1];
    const float w2 = w[d * 4 + 2], w3 = w[d * 4 + 3];

    if (!rev) {
        if (l >= 3) acc = fmaf(w0, xin[(size_t)(base_bl + l - 3) * DINNER + d], acc);
        if (l >= 2) acc = fmaf(w1, xin[(size_t)(base_bl + l - 2) * DINNER + d], acc);
        if (l >= 1) acc = fmaf(w2, xin[(size_t)(base_bl + l - 1) * DINNER + d], acc);
        acc = fmaf(w3, xin[(size_t)t * DINNER + d], acc);
    } else {
        acc = fmaf(w3, xin[(size_t)t * DINNER + d], acc);
        if (l + 1 < L_SEQ) acc = fmaf(w2, xin[(size_t)(base_bl + l + 1) * DINNER + d], acc);
        if (l + 2 < L_SEQ) acc = fmaf(w1, xin[(size_t)(base_bl + l + 2) * DINNER + d], acc);
        if (l + 3 < L_SEQ) acc = fmaf(w0, xin[(size_t)(base_bl + l + 3) * DINNER + d], acc);
    }
    xout[gidx] = acc * sigmoidf_(acc);
}

// ---------------------------------------------------------------------------
// Chunk-parallel selective scan.
//
// Chain recurrence per (br,b,d,n):  h_t = dA_t h_{t-1} + dt_t B_t xi_t
// Split L into NCHUNK chunks of CHUNK. Scan-order position p = rev ? 31-cc : cc.
//
// pass1: per-chunk local scan from h=0 -> h_end_local + per-(d,chunk) sum(dt)
// pass2: sequential combine over p (in-place h buffer -> h_init per chunk)
// pass3: local scan from h_init, fused y = (sum_n h C + xi D) * silu(z)
//
// h buffer layout: [br][b][p][dg(64)][dl(16)][n(16)]  (tid-contiguous/block)
// sdt buffer:      [br][b][p][d(1024)]
// ---------------------------------------------------------------------------
__global__ __launch_bounds__(256) void scan_part1_k(
    const float* __restrict__ dt0, const float* __restrict__ dt1,
    const float* __restrict__ xi0, const float* __restrict__ xi1,
    const float* __restrict__ xd0, const float* __restrict__ xd1,
    const float* __restrict__ Al0, const float* __restrict__ Al1,
    float* __restrict__ hbuf, float* __restrict__ sdtbuf)
{
    const int bid = blockIdx.x;
    const int dg  = bid & 63;
    const int cc  = (bid >> 6) & 31;
    const int b   = (bid >> 11) & 1;
    const int br  = bid >> 12;
    const int rev = br;
    const int p   = rev ? (NCHUNK - 1 - cc) : cc;
    const int d0  = dg << 4;

    const float* dt = br ? dt1 : dt0;
    const float* xi = br ? xi1 : xi0;
    const float* xd = br ? xd1 : xd0;
    const float* Al = br ? Al1 : Al0;

    const int tid = threadIdx.x;
    const int dl  = tid >> 4;
    const int n   = tid & 15;
    const int d   = d0 + dl;

    const float A2 = -__expf(Al[d * DSTATE + n]) * 1.44269504f;

    __shared__ float s_dt[CHUNK][16];
    __shared__ float s_xi[CHUNK][16];
    __shared__ float s_b [CHUNK][16];

    const int lrow = tid >> 2;
    const int lcol = (tid & 3) << 2;

    const size_t rowTok = (size_t)b * L_SEQ + cc * CHUNK + lrow;
    *(float4*)(&s_dt[lrow][lcol]) = *(const float4*)(dt + rowTok * DINNER + d0 + lcol);
    *(float4*)(&s_xi[lrow][lcol]) = *(const float4*)(xi + rowTok * DINNER + d0 + lcol);
    *(float4*)(&s_b [lrow][lcol]) = *(const float4*)(xd + rowTok * 64 + 32 + lcol);
    __syncthreads();

    float h = 0.0f, sdt = 0.0f;
    #pragma unroll 8
    for (int r = 0; r < CHUNK; ++r) {
        const int rr = rev ? (CHUNK - 1 - r) : r;
        const float dtv = s_dt[rr][dl];
        const float xiv = s_xi[rr][dl];
        const float bv  = s_b [rr][n];
        const float dA  = exp2f(dtv * A2);
        h = fmaf(dA, h, dtv * bv * xiv);
        sdt += dtv;
    }

    const size_t hoff = ((size_t)(((br * 2 + b) * NCHUNK + p) * 64 + dg) << 8) + tid;
    hbuf[hoff] = h;
    if (n == 0)
        sdtbuf[(size_t)((br * 2 + b) * NCHUNK + p) * DINNER + d] = sdt;
}

__global__ __launch_bounds__(256) void scan_combine_k(
    float* __restrict__ hbuf, const float* __restrict__ sdtbuf,
    const float* __restrict__ Al0, const float* __restrict__ Al1)
{
    const int gid = blockIdx.x * 256 + threadIdx.x;   // 65536 chains
    const int br  = gid >> 15;
    const int rem = gid & 32767;
    const int b   = rem >> 14;
    const int cid = rem & 16383;       // d*16 + n
    const int d   = cid >> 4;
    const int n   = cid & 15;

    const float* Al = br ? Al1 : Al0;
    const float A2 = -__expf(Al[d * DSTATE + n]) * 1.44269504f;

    const size_t hbase = (size_t)((br * 2 + b) * NCHUNK) * 16384 + cid;
    const size_t sbase = (size_t)((br * 2 + b) * NCHUNK) * DINNER + d;

    float hi = 0.0f;
    #pragma unroll 8
    for (int pch = 0; pch < NCHUNK; ++pch) {
        const size_t off = hbase + (size_t)pch * 16384;
        const float he = hbuf[off];
        const float ap = exp2f(A2 * sdtbuf[sbase + (size_t)pch * DINNER]);
        hbuf[off] = hi;
        hi = fmaf(ap, hi, he);
    }
}

__global__ __launch_bounds__(256) void scan_part3_k(
    const float* __restrict__ dt0, const float* __restrict__ dt1,
    const float* __restrict__ xi0, const float* __restrict__ xi1,
    const float* __restrict__ z0,  const float* __restrict__ z1,
    const float* __restrict__ xd0, const float* __restrict__ xd1,
    float* __restrict__ y0,        float* __restrict__ y1,
    const float* __restrict__ Al0, const float* __restrict__ Al1,
    const float* __restrict__ D0,  const float* __restrict__ D1,
    const float* __restrict__ hbuf)
{
    const int bid = blockIdx.x;
    const int dg  = bid & 63;
    const int cc  = (bid >> 6) & 31;
    const int b   = (bid >> 11) & 1;
    const int br  = bid >> 12;
    const int rev = br;
    const int p   = rev ? (NCHUNK - 1 - cc) : cc;
    const int d0  = dg << 4;

    const float* dt = br ? dt1 : dt0;
    const float* xi = br ? xi1 : xi0;
    const float* zz = br ? z1  : z0;
    const float* xd = br ? xd1 : xd0;
    float*       y  = br ? y1  : y0;
    const float* Al = br ? Al1 : Al0;
    const float* Dp = br ? D1  : D0;

    const int tid = threadIdx.x;
    const int dl  = tid >> 4;
    const int n   = tid & 15;
    const int d   = d0 + dl;

    const float A2 = -__expf(Al[d * DSTATE + n]) * 1.44269504f;
    const float Dd = Dp[d];

    __shared__ float s_dt[CHUNK][16];
    __shared__ float s_xi[CHUNK][16];
    __shared__ float s_z [CHUNK][16];
    __shared__ float s_bc[CHUNK][32];
    __shared__ float s_y [CHUNK][16];

    const int lrow = tid >> 2;
    const int lcol = (tid & 3) << 2;
    const int bcol = (tid & 3) << 3;

    const size_t rowTok = (size_t)b * L_SEQ + cc * CHUNK + lrow;
    *(float4*)(&s_dt[lrow][lcol])     = *(const float4*)(dt + rowTok * DINNER + d0 + lcol);
    *(float4*)(&s_xi[lrow][lcol])     = *(const float4*)(xi + rowTok * DINNER + d0 + lcol);
    *(float4*)(&s_z [lrow][lcol])     = *(const float4*)(zz + rowTok * DINNER + d0 + lcol);
    *(float4*)(&s_bc[lrow][bcol])     = *(const float4*)(xd + rowTok * 64 + 32 + bcol);
    *(float4*)(&s_bc[lrow][bcol + 4]) = *(const float4*)(xd + rowTok * 64 + 36 + bcol);

    const size_t hoff = ((size_t)(((br * 2 + b) * NCHUNK + p) * 64 + dg) << 8) + tid;
    float h = hbuf[hoff];
    __syncthreads();

    #pragma unroll 4
    for (int r = 0; r < CHUNK; ++r) {
        const int rr = rev ? (CHUNK - 1 - r) : r;
        const float dtv = s_dt[rr][dl];
        const float xiv = s_xi[rr][dl];
        const float bv  = s_bc[rr][n];
        const float cv  = s_bc[rr][16 + n];
        const float dA  = exp2f(dtv * A2);
        h = fmaf(dA, h, dtv * bv * xiv);
        float pr = h * cv;
        pr += __shfl_xor(pr, 1, 64);
        pr += __shfl_xor(pr, 2, 64);
        pr += __shfl_xor(pr, 4, 64);
        pr += __shfl_xor(pr, 8, 64);
        if (n == 0) {
            const float zv = s_z[rr][dl];
            s_y[rr][dl] = (pr + xiv * Dd) * (zv * sigmoidf_(zv));
        }
    }
    __syncthreads();
    *(float4*)(y + rowTok * DINNER + d0 + lcol) = *(const float4*)(&s_y[lrow][lcol]);
}

// ---------------------------------------------------------------------------
extern "C" void kernel_launch(void* const* d_in, const int* in_sizes, int n_in,
                              void* d_out, int out_size, void* d_ws, size_t ws_size,
                              hipStream_t stream)
{
    const float* x      = (const float*)d_in[0];
    const float* ln_g   = (const float*)d_in[1];
    const float* ln_b   = (const float*)d_in[2];
    const float* proj_w = (const float*)d_in[3];
    const float* proj_b = (const float*)d_in[4];
    const float* p_in_w[2]   = {(const float*)d_in[5],  (const float*)d_in[14]};
    const float* p_conv_w[2] = {(const float*)d_in[6],  (const float*)d_in[15]};
    const float* p_conv_b[2] = {(const float*)d_in[7],  (const float*)d_in[16]};
    const float* p_xproj[2]  = {(const float*)d_in[8],  (const float*)d_in[17]};
    const float* p_dt_w[2]   = {(const float*)d_in[9],  (const float*)d_in[18]};
    const float* p_dt_b[2]   = {(const float*)d_in[10], (const float*)d_in[19]};
    const float* p_Alog[2]   = {(const float*)d_in[11], (const float*)d_in[20]};
    const float* p_D[2]      = {(const float*)d_in[12], (const float*)d_in[21]};
    const float* p_out_w[2]  = {(const float*)d_in[13], (const float*)d_in[22]};

    float* ws = (float*)d_ws;
    size_t o = 0;
    float* xn = ws;                o += (size_t)NTOK * DMODEL;
    float *xiraw[2], *zb[2], *xib[2], *xdb[2], *dtb[2];
    for (int br = 0; br < 2; ++br) {
        xiraw[br] = ws + o;  o += (size_t)NTOK * DINNER;   // reused as y after scan
        zb[br]    = ws + o;  o += (size_t)NTOK * DINNER;
        xib[br]   = ws + o;  o += (size_t)NTOK * DINNER;
        xdb[br]   = ws + o;  o += (size_t)NTOK * 64;
        dtb[br]   = ws + o;  o += (size_t)NTOK * DINNER;
    }
    float* fbsum = ws + o;         o += (size_t)NTOK * DMODEL;
    float* hbuf  = ws + o;         o += (size_t)4 * NCHUNK * 16384;   // 4.2M floats
    float* sdtb  = ws + o;         o += (size_t)4 * NCHUNK * DINNER;  // 131K floats

    const dim3 blk(256);

    ln_k<<<NTOK / 4, blk, 0, stream>>>(x, ln_g, ln_b, xn);

    for (int br = 0; br < 2; ++br) {
        gemm_k<0><<<dim3(DINNER / 64, NTOK / 64), blk, 0, stream>>>(
            xn, DMODEL, p_in_w[br], 2 * DINNER, xiraw[br], DINNER, DMODEL,
            nullptr, nullptr, 0);
        gemm_k<0><<<dim3(DINNER / 64, NTOK / 64), blk, 0, stream>>>(
            xn, DMODEL, p_in_w[br] + DINNER, 2 * DINNER, zb[br], DINNER, DMODEL,
            nullptr, nullptr, 0);
        conv_silu_k<<<NTOK * DINNER / 256, blk, 0, stream>>>(
            xiraw[br], p_conv_w[br], p_conv_b[br], xib[br], br);
        gemm_k<0><<<dim3(1, NTOK / 64), blk, 0, stream>>>(
            xib[br], DINNER, p_xproj[br], 64, xdb[br], 64, DINNER,
            nullptr, nullptr, 0);
        gemm_k<1><<<dim3(DINNER / 64, NTOK / 64), blk, 0, stream>>>(
            xdb[br], 64, p_dt_w[br], DINNER, dtb[br], DINNER, DTRANK,
            p_dt_b[br], nullptr, 0);
    }

    // chunk-parallel bidirectional scan (both branches in each launch)
    scan_part1_k<<<2 * 2 * NCHUNK * 64, blk, 0, stream>>>(
        dtb[0], dtb[1], xib[0], xib[1], xdb[0], xdb[1],
        p_Alog[0], p_Alog[1], hbuf, sdtb);
    scan_combine_k<<<65536 / 256, blk, 0, stream>>>(
        hbuf, sdtb, p_Alog[0], p_Alog[1]);
    scan_part3_k<<<2 * 2 * NCHUNK * 64, blk, 0, stream>>>(
        dtb[0], dtb[1], xib[0], xib[1], zb[0], zb[1], xdb[0], xdb[1],
        xiraw[0], xiraw[1], p_Alog[0], p_Alog[1], p_D[0], p_D[1], hbuf);

    gemm_k<0><<<dim3(DMODEL / 64, NTOK / 64), blk, 0, stream>>>(
        xiraw[0], DINNER, p_out_w[0], DMODEL, fbsum, DMODEL, DINNER,
        nullptr, nullptr, 0);
    gemm_k<2><<<dim3(DMODEL / 64, NTOK / 64), blk, 0, stream>>>(
        xiraw[1], DINNER, p_out_w[1], DMODEL, fbsum, DMODEL, DINNER,
        nullptr, nullptr, 0);

    gemm_k<3><<<dim3(DMODEL / 64, NTOK / 64), blk, 0, stream>>>(
        fbsum, DMODEL, proj_w, DMODEL, (float*)d_out, DMODEL, DMODEL,
        proj_b, x, DMODEL);
}

// Round 6
// 524.582 us; speedup vs baseline: 2.4778x; 1.7915x over previous
//
#include <hip/hip_runtime.h>
#include <hip/hip_bf16.h>
#include <math.h>

#define L_SEQ  2048
#define NTOK   4096
#define DMODEL 512
#define DINNER 1024
#define DSTATE 16
#define NCHUNK 32
#define CHUNK  64

typedef unsigned short u16;
typedef float f32x4 __attribute__((ext_vector_type(4)));
typedef __bf16 bf16x8 __attribute__((ext_vector_type(8)));

__device__ __forceinline__ float sigmoidf_(float x) {
    return 1.0f / (1.0f + __expf(-x));
}
__device__ __forceinline__ u16 f2bf(float f) {
    __hip_bfloat16 h = __float2bfloat16(f);
    return __builtin_bit_cast(u16, h);
}
__device__ __forceinline__ float bf2f(u16 u) {
    return __bfloat162float(__builtin_bit_cast(__hip_bfloat16, u));
}

// ---------------------------------------------------------------------------
// Transpose + cast fp32 [R][C] -> bf16 [C][R]
// ---------------------------------------------------------------------------
__global__ __launch_bounds__(256) void tcast_k(const float* __restrict__ in,
                                               u16* __restrict__ out,
                                               int R, int C)
{
    __shared__ u16 t[32][33];
    const int cl = threadIdx.x & 31;
    const int rl = threadIdx.x >> 5;      // 0..7
    const int bc = blockIdx.x << 5;       // col tile
    const int br = blockIdx.y << 5;       // row tile
    #pragma unroll
    for (int i = 0; i < 4; ++i) {
        int r = rl + i * 8;
        t[r][cl] = f2bf(in[(size_t)(br + r) * C + bc + cl]);
    }
    __syncthreads();
    #pragma unroll
    for (int i = 0; i < 4; ++i) {
        int r = rl + i * 8;
        out[(size_t)(bc + r) * R + br + cl] = t[cl][r];
    }
}

// ---------------------------------------------------------------------------
// LayerNorm -> bf16 output
// ---------------------------------------------------------------------------
__global__ __launch_bounds__(256) void ln_k(const float* __restrict__ x,
                                            const float* __restrict__ g,
                                            const float* __restrict__ b,
                                            u16* __restrict__ xn)
{
    const int w    = threadIdx.x >> 6;
    const int lane = threadIdx.x & 63;
    const int row  = (blockIdx.x << 2) + w;
    const float* xr = x + (size_t)row * DMODEL;

    float4 v0 = *(const float4*)(xr + lane * 8);
    float4 v1 = *(const float4*)(xr + lane * 8 + 4);

    float s = v0.x + v0.y + v0.z + v0.w + v1.x + v1.y + v1.z + v1.w;
    #pragma unroll
    for (int o = 1; o < 64; o <<= 1) s += __shfl_xor(s, o, 64);
    const float mu = s * (1.0f / DMODEL);

    float d0 = v0.x - mu, d1 = v0.y - mu, d2 = v0.z - mu, d3 = v0.w - mu;
    float d4 = v1.x - mu, d5 = v1.y - mu, d6 = v1.z - mu, d7 = v1.w - mu;
    float ss = d0*d0 + d1*d1 + d2*d2 + d3*d3 + d4*d4 + d5*d5 + d6*d6 + d7*d7;
    #pragma unroll
    for (int o = 1; o < 64; o <<= 1) ss += __shfl_xor(ss, o, 64);
    const float rs = rsqrtf(ss * (1.0f / DMODEL) + 1e-5f);

    float4 g0 = *(const float4*)(g + lane * 8);
    float4 g1 = *(const float4*)(g + lane * 8 + 4);
    float4 b0 = *(const float4*)(b + lane * 8);
    float4 b1 = *(const float4*)(b + lane * 8 + 4);

    u16 o8[8];
    o8[0] = f2bf(d0 * rs * g0.x + b0.x);
    o8[1] = f2bf(d1 * rs * g0.y + b0.y);
    o8[2] = f2bf(d2 * rs * g0.z + b0.z);
    o8[3] = f2bf(d3 * rs * g0.w + b0.w);
    o8[4] = f2bf(d4 * rs * g1.x + b1.x);
    o8[5] = f2bf(d5 * rs * g1.y + b1.y);
    o8[6] = f2bf(d6 * rs * g1.z + b1.z);
    o8[7] = f2bf(d7 * rs * g1.w + b1.w);
    uint pk0 = (uint)o8[0] | ((uint)o8[1] << 16);
    uint pk1 = (uint)o8[2] | ((uint)o8[3] << 16);
    uint pk2 = (uint)o8[4] | ((uint)o8[5] << 16);
    uint pk3 = (uint)o8[6] | ((uint)o8[7] << 16);
    uint4 pk = make_uint4(pk0, pk1, pk2, pk3);
    *(uint4*)(xn + (size_t)row * DMODEL + lane * 8) = pk;
}

// ---------------------------------------------------------------------------
// bf16 MFMA GEMM: C[M,N] = A[M,K] (bf16, row-major) x B^T[N,K] (bf16, row-major)
// 256 threads = 4 waves. Swizzled LDS (16B slots, slot ^= row&SMASK).
// EPI: 0=fp32 store, 1=fp32+bf16, 2=softplus(acc+bias) fp32, 3=acc+bias+resid,
//      4=bf16 only.  BR2: branch via blockIdx.z.  DUAL: two A/B pairs, acc sum.
// ---------------------------------------------------------------------------
template<int BM, int BN, int BK, int WGM, int WGN, int EPI, bool BR2, bool DUAL>
__global__ __launch_bounds__(256) void gemm_bf16_k(
    const u16* __restrict__ A0, const u16* __restrict__ A1, int lda,
    const u16* __restrict__ B0, const u16* __restrict__ B1, int ldb,
    float* __restrict__ C0f, float* __restrict__ C1f,
    u16* __restrict__ C0h, u16* __restrict__ C1h, int ldc,
    int K,
    const float* __restrict__ bias0, const float* __restrict__ bias1,
    const float* __restrict__ resid)
{
    constexpr int SPR   = BK / 8;        // 16B slots per row
    constexpr int SMASK = SPR - 1;
    constexpr int NSA   = BM * SPR / 256;
    constexpr int NSB   = BN * SPR / 256;
    constexpr int WTM   = BM / WGM;
    constexpr int WTN   = BN / WGN;
    constexpr int FM    = WTM / 16;
    constexpr int FN    = WTN / 16;
    constexpr int KH    = BK / 32;

    __shared__ u16 Alds[BM * BK];
    __shared__ u16 Blds[BN * BK];

    const int tid = threadIdx.x;
    const int brz = BR2 ? blockIdx.z : 0;
    const u16* Ag = brz ? A1 : A0;
    const u16* Bg = brz ? B1 : B0;
    float* Cf     = brz ? C1f : C0f;
    u16*   Ch     = brz ? C1h : C0h;
    const float* bias = brz ? bias1 : bias0;

    const int bm = blockIdx.y * BM;
    const int bn = blockIdx.x * BN;

    const int l   = tid & 63;
    const int wid = tid >> 6;
    const int wm  = wid / WGN;
    const int wn  = wid % WGN;
    const int lr  = l & 15;
    const int lk  = l >> 4;

    f32x4 acc[FM][FN] = {};

    for (int s = 0; s < (DUAL ? 2 : 1); ++s) {
        const u16* As = DUAL ? (s ? A1 : A0) : Ag;
        const u16* Bs = DUAL ? (s ? B1 : B0) : Bg;

        uint4 ra[NSA], rb[NSB];
        #pragma unroll
        for (int i = 0; i < NSA; ++i) {
            int lin = i * 256 + tid, row = lin / SPR, c = lin & SMASK;
            ra[i] = *(const uint4*)(As + (size_t)(bm + row) * lda + c * 8);
        }
        #pragma unroll
        for (int i = 0; i < NSB; ++i) {
            int lin = i * 256 + tid, row = lin / SPR, c = lin & SMASK;
            rb[i] = *(const uint4*)(Bs + (size_t)(bn + row) * ldb + c * 8);
        }

        for (int k0 = 0; k0 < K; k0 += BK) {
            __syncthreads();
            #pragma unroll
            for (int i = 0; i < NSA; ++i) {
                int lin = i * 256 + tid, row = lin / SPR, c = lin & SMASK;
                *(uint4*)(&Alds[(row * SPR + (c ^ (row & SMASK))) * 8]) = ra[i];
            }
            #pragma unroll
            for (int i = 0; i < NSB; ++i) {
                int lin = i * 256 + tid, row = lin / SPR, c = lin & SMASK;
                *(uint4*)(&Blds[(row * SPR + (c ^ (row & SMASK))) * 8]) = rb[i];
            }
            __syncthreads();
            if (k0 + BK < K) {
                #pragma unroll
                for (int i = 0; i < NSA; ++i) {
                    int lin = i * 256 + tid, row = lin / SPR, c = lin & SMASK;
                    ra[i] = *(const uint4*)(As + (size_t)(bm + row) * lda + k0 + BK + c * 8);
                }
                #pragma unroll
                for (int i = 0; i < NSB; ++i) {
                    int lin = i * 256 + tid, row = lin / SPR, c = lin & SMASK;
                    rb[i] = *(const uint4*)(Bs + (size_t)(bn + row) * ldb + k0 + BK + c * 8);
                }
            }
            #pragma unroll
            for (int kh = 0; kh < KH; ++kh) {
                bf16x8 af[FM], bfr[FN];
                #pragma unroll
                for (int m = 0; m < FM; ++m) {
                    int row = wm * WTM + m * 16 + lr;
                    int c   = kh * 4 + lk;
                    af[m] = *(const bf16x8*)(&Alds[(row * SPR + (c ^ (row & SMASK))) * 8]);
                }
                #pragma unroll
                for (int n = 0; n < FN; ++n) {
                    int row = wn * WTN + n * 16 + lr;
                    int c   = kh * 4 + lk;
                    bfr[n] = *(const bf16x8*)(&Blds[(row * SPR + (c ^ (row & SMASK))) * 8]);
                }
                #pragma unroll
                for (int m = 0; m < FM; ++m)
                    #pragma unroll
                    for (int n = 0; n < FN; ++n)
                        acc[m][n] = __builtin_amdgcn_mfma_f32_16x16x32_bf16(
                            af[m], bfr[n], acc[m][n], 0, 0, 0);
            }
        }
    }

    #pragma unroll
    for (int m = 0; m < FM; ++m) {
        #pragma unroll
        for (int n = 0; n < FN; ++n) {
            const int rowb = bm + wm * WTM + m * 16 + (l >> 4) * 4;
            const int col  = bn + wn * WTN + n * 16 + (l & 15);
            #pragma unroll
            for (int j = 0; j < 4; ++j) {
                const int row = rowb + j;
                float v = acc[m][n][j];
                if (EPI == 2) {
                    float t = v + bias[col];
                    v = (t > 20.0f) ? t : log1pf(__expf(t));
                }
                if (EPI == 3) {
                    v += bias[col] + resid[(size_t)row * ldc + col];
                }
                if (EPI != 4) Cf[(size_t)row * ldc + col] = v;
                if (EPI == 1 || EPI == 4) Ch[(size_t)row * ldc + col] = f2bf(v);
            }
        }
    }
}

// ---------------------------------------------------------------------------
// Depthwise conv k=4 (causal fwd / anticausal bwd) + bias + SiLU -> bf16
// Input xz[br] has ld 2048 (xi = cols 0:1024). Both branches in one launch.
// ---------------------------------------------------------------------------
__global__ __launch_bounds__(256) void conv_silu_k(
    const float* __restrict__ xz0, const float* __restrict__ xz1,
    const float* __restrict__ w0,  const float* __restrict__ w1,
    const float* __restrict__ cb0, const float* __restrict__ cb1,
    u16* __restrict__ xo0,         u16* __restrict__ xo1)
{
    const int idx = blockIdx.x * 256 + threadIdx.x;
    const int br  = idx >> 22;
    const int g   = idx & ((1 << 22) - 1);
    const float* xin = br ? xz1 : xz0;
    const float* w   = br ? w1  : w0;
    const float* cb  = br ? cb1 : cb0;
    u16* xo          = br ? xo1 : xo0;

    const int d = g & (DINNER - 1);
    const int t = g >> 10;
    const int l = t & (L_SEQ - 1);
    const int base = t - l;

    float acc = cb[d];
    float4 wv = *(const float4*)(w + d * 4);

    if (!br) {
        if (l >= 3) acc = fmaf(wv.x, xin[(size_t)(base + l - 3) * 2048 + d], acc);
        if (l >= 2) acc = fmaf(wv.y, xin[(size_t)(base + l - 2) * 2048 + d], acc);
        if (l >= 1) acc = fmaf(wv.z, xin[(size_t)(base + l - 1) * 2048 + d], acc);
        acc = fmaf(wv.w, xin[(size_t)t * 2048 + d], acc);
    } else {
        acc = fmaf(wv.w, xin[(size_t)t * 2048 + d], acc);
        if (l + 1 < L_SEQ) acc = fmaf(wv.z, xin[(size_t)(base + l + 1) * 2048 + d], acc);
        if (l + 2 < L_SEQ) acc = fmaf(wv.y, xin[(size_t)(base + l + 2) * 2048 + d], acc);
        if (l + 3 < L_SEQ) acc = fmaf(wv.x, xin[(size_t)(base + l + 3) * 2048 + d], acc);
    }
    xo[g] = f2bf(acc * sigmoidf_(acc));
}

// ---------------------------------------------------------------------------
// Chunk-parallel scan, thread-owns-d layout. h[16] in registers.
// bid = ((br*2+b)*32 + cc)*4 + dq ; thread owns d = dq*256 + tid.
// ---------------------------------------------------------------------------
__global__ __launch_bounds__(256) void scan1_k(
    const float* __restrict__ dt0, const float* __restrict__ dt1,
    const u16*  __restrict__ xi0, const u16*  __restrict__ xi1,
    const float* __restrict__ xd0, const float* __restrict__ xd1,
    const float* __restrict__ Al0, const float* __restrict__ Al1,
    float* __restrict__ hbuf, float* __restrict__ sdtbuf)
{
    const int bid = blockIdx.x;
    const int dq  = bid & 3;
    const int cc  = (bid >> 2) & 31;
    const int b   = (bid >> 7) & 1;
    const int br  = bid >> 8;
    const int rev = br;
    const int p   = rev ? (NCHUNK - 1 - cc) : cc;
    const int tid = threadIdx.x;
    const int d   = dq * 256 + tid;

    const float* dt = br ? dt1 : dt0;
    const u16*  xi  = br ? xi1 : xi0;
    const float* xd = br ? xd1 : xd0;
    const float* Al = br ? Al1 : Al0;

    float A2[16];
    #pragma unroll
    for (int i = 0; i < 4; ++i) {
        float4 a = *(const float4*)(Al + (size_t)d * 16 + i * 4);
        A2[i*4+0] = -__expf(a.x) * 1.44269504f;
        A2[i*4+1] = -__expf(a.y) * 1.44269504f;
        A2[i*4+2] = -__expf(a.z) * 1.44269504f;
        A2[i*4+3] = -__expf(a.w) * 1.44269504f;
    }

    __shared__ float s_b[CHUNK][16];
    const int rtB = b * L_SEQ + cc * CHUNK;
    {
        int row = tid >> 2, q = (tid & 3) * 4;
        *(float4*)&s_b[row][q] = *(const float4*)(xd + (size_t)(rtB + row) * 64 + 32 + q);
    }
    __syncthreads();

    float h[16] = {};
    float sdt = 0.0f;
    int rr = rev ? 63 : 0;
    float dtc = dt[(size_t)(rtB + rr) * DINNER + d];
    float xic = bf2f(xi[(size_t)(rtB + rr) * DINNER + d]);

    for (int r = 0; r < CHUNK; ++r) {
        float dtn = 0.0f, xin_ = 0.0f;
        if (r < CHUNK - 1) {
            const int rrn = rev ? (62 - r) : (r + 1);
            dtn  = dt[(size_t)(rtB + rrn) * DINNER + d];
            xin_ = bf2f(xi[(size_t)(rtB + rrn) * DINNER + d]);
        }
        float bv[16];
        *(float4*)&bv[0]  = *(const float4*)&s_b[rr][0];
        *(float4*)&bv[4]  = *(const float4*)&s_b[rr][4];
        *(float4*)&bv[8]  = *(const float4*)&s_b[rr][8];
        *(float4*)&bv[12] = *(const float4*)&s_b[rr][12];
        const float common = dtc * xic;
        #pragma unroll
        for (int n = 0; n < 16; ++n)
            h[n] = fmaf(exp2f(dtc * A2[n]), h[n], common * bv[n]);
        sdt += dtc;
        dtc = dtn; xic = xin_;
        rr = rev ? (62 - r) : (r + 1);
    }

    float4* hp = (float4*)(hbuf + ((size_t)((br * 2 + b) * NCHUNK + p) * DINNER + d) * 16);
    hp[0] = make_float4(h[0],  h[1],  h[2],  h[3]);
    hp[1] = make_float4(h[4],  h[5],  h[6],  h[7]);
    hp[2] = make_float4(h[8],  h[9],  h[10], h[11]);
    hp[3] = make_float4(h[12], h[13], h[14], h[15]);
    sdtbuf[(size_t)((br * 2 + b) * NCHUNK + p) * DINNER + d] = sdt;
}

__global__ __launch_bounds__(256) void scan2_k(
    float* __restrict__ hbuf, const float* __restrict__ sdtbuf,
    const float* __restrict__ Al0, const float* __restrict__ Al1)
{
    const int gid = blockIdx.x * 256 + threadIdx.x;   // 65536
    const int br  = gid >> 15;
    const int b   = (gid >> 14) & 1;
    const int cid = gid & 16383;
    const int d   = cid >> 4;
    const float* Al = br ? Al1 : Al0;
    const float A2 = -__expf(Al[cid]) * 1.44269504f;
    const int bb = (br * 2 + b) * NCHUNK;

    float hi = 0.0f;
    for (int pp = 0; pp < NCHUNK; ++pp) {
        const size_t off = (size_t)(bb + pp) * 16384 + cid;
        const float he = hbuf[off];
        const float ap = exp2f(A2 * sdtbuf[(size_t)(bb + pp) * DINNER + d]);
        hbuf[off] = hi;
        hi = fmaf(ap, hi, he);
    }
}

__global__ __launch_bounds__(256) void scan3_k(
    const float* __restrict__ dt0, const float* __restrict__ dt1,
    const u16*  __restrict__ xi0, const u16*  __restrict__ xi1,
    const float* __restrict__ xz0, const float* __restrict__ xz1,
    const float* __restrict__ xd0, const float* __restrict__ xd1,
    u16* __restrict__ y0,          u16* __restrict__ y1,
    const float* __restrict__ Al0, const float* __restrict__ Al1,
    const float* __restrict__ D0,  const float* __restrict__ D1,
    const float* __restrict__ hbuf)
{
    const int bid = blockIdx.x;
    const int dq  = bid & 3;
    const int cc  = (bid >> 2) & 31;
    const int b   = (bid >> 7) & 1;
    const int br  = bid >> 8;
    const int rev = br;
    const int p   = rev ? (NCHUNK - 1 - cc) : cc;
    const int tid = threadIdx.x;
    const int d   = dq * 256 + tid;

    const float* dt = br ? dt1 : dt0;
    const u16*  xi  = br ? xi1 : xi0;
    const float* zz = (br ? xz1 : xz0) + DINNER;   // z = cols 1024:2048, ld 2048
    const float* xd = br ? xd1 : xd0;
    u16* y          = br ? y1  : y0;
    const float* Al = br ? Al1 : Al0;
    const float Dd  = (br ? D1 : D0)[d];

    float A2[16];
    #pragma unroll
    for (int i = 0; i < 4; ++i) {
        float4 a = *(const float4*)(Al + (size_t)d * 16 + i * 4);
        A2[i*4+0] = -__expf(a.x) * 1.44269504f;
        A2[i*4+1] = -__expf(a.y) * 1.44269504f;
        A2[i*4+2] = -__expf(a.z) * 1.44269504f;
        A2[i*4+3] = -__expf(a.w) * 1.44269504f;
    }

    __shared__ float s_bc[CHUNK][32];
    const int rtB = b * L_SEQ + cc * CHUNK;
    {
        int row = tid >> 2, q = (tid & 3) * 8;
        *(float4*)&s_bc[row][q]     = *(const float4*)(xd + (size_t)(rtB + row) * 64 + 32 + q);
        *(float4*)&s_bc[row][q + 4] = *(const float4*)(xd + (size_t)(rtB + row) * 64 + 36 + q);
    }

    float h[16];
    {
        const float4* hp = (const float4*)(hbuf + ((size_t)((br * 2 + b) * NCHUNK + p) * DINNER + d) * 16);
        float4 h0 = hp[0], h1 = hp[1], h2 = hp[2], h3 = hp[3];
        h[0]=h0.x; h[1]=h0.y; h[2]=h0.z; h[3]=h0.w;
        h[4]=h1.x; h[5]=h1.y; h[6]=h1.z; h[7]=h1.w;
        h[8]=h2.x; h[9]=h2.y; h[10]=h2.z; h[11]=h2.w;
        h[12]=h3.x; h[13]=h3.y; h[14]=h3.z; h[15]=h3.w;
    }
    __syncthreads();

    int rr = rev ? 63 : 0;
    float dtc = dt[(size_t)(rtB + rr) * DINNER + d];
    float xic = bf2f(xi[(size_t)(rtB + rr) * DINNER + d]);
    float zc  = zz[(size_t)(rtB + rr) * 2048 + d];

    for (int r = 0; r < CHUNK; ++r) {
        float dtn = 0.0f, xin_ = 0.0f, zn = 0.0f;
        if (r < CHUNK - 1) {
            const int rrn = rev ? (62 - r) : (r + 1);
            dtn  = dt[(size_t)(rtB + rrn) * DINNER + d];
            xin_ = bf2f(xi[(size_t)(rtB + rrn) * DINNER + d]);
            zn   = zz[(size_t)(rtB + rrn) * 2048 + d];
        }
        float bv[16], cv[16];
        *(float4*)&bv[0]  = *(const float4*)&s_bc[rr][0];
        *(float4*)&bv[4]  = *(const float4*)&s_bc[rr][4];
        *(float4*)&bv[8]  = *(const float4*)&s_bc[rr][8];
        *(float4*)&bv[12] = *(const float4*)&s_bc[rr][12];
        *(float4*)&cv[0]  = *(const float4*)&s_bc[rr][16];
        *(float4*)&cv[4]  = *(const float4*)&s_bc[rr][20];
        *(float4*)&cv[8]  = *(const float4*)&s_bc[rr][24];
        *(float4*)&cv[12] = *(const float4*)&s_bc[rr][28];
        const float common = dtc * xic;
        float acc = 0.0f;
        #pragma unroll
        for (int n = 0; n < 16; ++n) {
            h[n] = fmaf(exp2f(dtc * A2[n]), h[n], common * bv[n]);
            acc  = fmaf(h[n], cv[n], acc);
        }
        const float yv = (acc + xic * Dd) * (zc * sigmoidf_(zc));
        y[(size_t)(rtB + rr) * DINNER + d] = f2bf(yv);
        dtc = dtn; xic = xin_; zc = zn;
        rr = rev ? (62 - r) : (r + 1);
    }
}

// ---------------------------------------------------------------------------
extern "C" void kernel_launch(void* const* d_in, const int* in_sizes, int n_in,
                              void* d_out, int out_size, void* d_ws, size_t ws_size,
                              hipStream_t stream)
{
    const float* x      = (const float*)d_in[0];
    const float* ln_g   = (const float*)d_in[1];
    const float* ln_b   = (const float*)d_in[2];
    const float* proj_w = (const float*)d_in[3];
    const float* proj_b = (const float*)d_in[4];
    const float* p_in_w[2]   = {(const float*)d_in[5],  (const float*)d_in[14]};
    const float* p_conv_w[2] = {(const float*)d_in[6],  (const float*)d_in[15]};
    const float* p_conv_b[2] = {(const float*)d_in[7],  (const float*)d_in[16]};
    const float* p_xproj[2]  = {(const float*)d_in[8],  (const float*)d_in[17]};
    const float* p_dt_w[2]   = {(const float*)d_in[9],  (const float*)d_in[18]};
    const float* p_dt_b[2]   = {(const float*)d_in[10], (const float*)d_in[19]};
    const float* p_Alog[2]   = {(const float*)d_in[11], (const float*)d_in[20]};
    const float* p_D[2]      = {(const float*)d_in[12], (const float*)d_in[21]};
    const float* p_out_w[2]  = {(const float*)d_in[13], (const float*)d_in[22]};

    char* w = (char*)d_ws;
    auto alloc = [&](size_t bytes) -> void* {
        void* p = (void*)w;
        w += (bytes + 255) & ~(size_t)255;
        return p;
    };

    u16* xn_bf = (u16*)alloc((size_t)NTOK * DMODEL * 2);
    u16 *in_wT[2], *xprojT[2], *dt_wT[2], *out_wT[2];
    for (int br = 0; br < 2; ++br) {
        in_wT[br]  = (u16*)alloc((size_t)2048 * 512 * 2);
        xprojT[br] = (u16*)alloc((size_t)64 * 1024 * 2);
        dt_wT[br]  = (u16*)alloc((size_t)1024 * 32 * 2);
        out_wT[br] = (u16*)alloc((size_t)512 * 1024 * 2);
    }
    u16* proj_wT = (u16*)alloc((size_t)512 * 512 * 2);
    float *xz[2], *xdb[2], *dtb[2];
    u16 *xi_bf[2], *xdb_bf[2], *y_bf[2];
    for (int br = 0; br < 2; ++br) {
        xz[br]     = (float*)alloc((size_t)NTOK * 2048 * 4);
        xi_bf[br]  = (u16*)alloc((size_t)NTOK * DINNER * 2);
        xdb[br]    = (float*)alloc((size_t)NTOK * 64 * 4);
        xdb_bf[br] = (u16*)alloc((size_t)NTOK * 64 * 2);
        dtb[br]    = (float*)alloc((size_t)NTOK * DINNER * 4);
        y_bf[br]   = (u16*)alloc((size_t)NTOK * DINNER * 2);
    }
    u16* fbsum_bf = (u16*)alloc((size_t)NTOK * DMODEL * 2);
    float* hbuf   = (float*)alloc((size_t)4 * NCHUNK * 16384 * 4);
    float* sdtb   = (float*)alloc((size_t)4 * NCHUNK * DINNER * 4);

    const dim3 blk(256);

    // ---- weight transposes (fp32 [K][N] -> bf16 [N][K]) ----
    for (int br = 0; br < 2; ++br) {
        tcast_k<<<dim3(2048/32, 512/32), blk, 0, stream>>>(p_in_w[br], in_wT[br], 512, 2048);
        tcast_k<<<dim3(64/32, 1024/32),  blk, 0, stream>>>(p_xproj[br], xprojT[br], 1024, 64);
        tcast_k<<<dim3(1024/32, 32/32),  blk, 0, stream>>>(p_dt_w[br], dt_wT[br], 32, 1024);
        tcast_k<<<dim3(512/32, 1024/32), blk, 0, stream>>>(p_out_w[br], out_wT[br], 1024, 512);
    }
    tcast_k<<<dim3(512/32, 512/32), blk, 0, stream>>>(proj_w, proj_wT, 512, 512);

    // ---- LayerNorm -> bf16 ----
    ln_k<<<NTOK / 4, blk, 0, stream>>>(x, ln_g, ln_b, xn_bf);

    // ---- in-proj (fused xi|z, N=2048), both branches via z ----
    gemm_bf16_k<128,128,64, 2,2, 0, true,false>
        <<<dim3(2048/128, NTOK/128, 2), blk, 0, stream>>>(
        xn_bf, xn_bf, DMODEL, in_wT[0], in_wT[1], DMODEL,
        xz[0], xz[1], nullptr, nullptr, 2048, DMODEL, nullptr, nullptr, nullptr);

    // ---- conv + SiLU -> bf16 (both branches) ----
    conv_silu_k<<<2 * NTOK * DINNER / 256, blk, 0, stream>>>(
        xz[0], xz[1], p_conv_w[0], p_conv_w[1], p_conv_b[0], p_conv_b[1],
        xi_bf[0], xi_bf[1]);

    // ---- x-proj (N=64) -> fp32 (scan B/C) + bf16 (dt GEMM A) ----
    gemm_bf16_k<128,64,64, 4,1, 1, true,false>
        <<<dim3(1, NTOK/128, 2), blk, 0, stream>>>(
        xi_bf[0], xi_bf[1], DINNER, xprojT[0], xprojT[1], DINNER,
        xdb[0], xdb[1], xdb_bf[0], xdb_bf[1], 64, DINNER, nullptr, nullptr, nullptr);

    // ---- dt-proj (K=32) + softplus + bias ----
    gemm_bf16_k<128,128,32, 2,2, 2, true,false>
        <<<dim3(DINNER/128, NTOK/128, 2), blk, 0, stream>>>(
        xdb_bf[0], xdb_bf[1], 64, dt_wT[0], dt_wT[1], 32,
        dtb[0], dtb[1], nullptr, nullptr, DINNER, 32, p_dt_b[0], p_dt_b[1], nullptr);

    // ---- chunk-parallel bidirectional scan ----
    scan1_k<<<512, blk, 0, stream>>>(dtb[0], dtb[1], xi_bf[0], xi_bf[1],
                                     xdb[0], xdb[1], p_Alog[0], p_Alog[1],
                                     hbuf, sdtb);
    scan2_k<<<65536 / 256, blk, 0, stream>>>(hbuf, sdtb, p_Alog[0], p_Alog[1]);
    scan3_k<<<512, blk, 0, stream>>>(dtb[0], dtb[1], xi_bf[0], xi_bf[1],
                                     xz[0], xz[1], xdb[0], xdb[1],
                                     y_bf[0], y_bf[1], p_Alog[0], p_Alog[1],
                                     p_D[0], p_D[1], hbuf);

    // ---- out-proj: fbsum = y0 @ out_w0 + y1 @ out_w1 (DUAL), bf16 out ----
    gemm_bf16_k<128,128,64, 2,2, 4, false,true>
        <<<dim3(DMODEL/128, NTOK/128, 1), blk, 0, stream>>>(
        y_bf[0], y_bf[1], DINNER, out_wT[0], out_wT[1], DINNER,
        nullptr, nullptr, fbsum_bf, nullptr, DMODEL, DINNER, nullptr, nullptr, nullptr);

    // ---- final: out = fbsum @ proj_w + proj_b + x ----
    gemm_bf16_k<128,128,64, 2,2, 3, false,false>
        <<<dim3(DMODEL/128, NTOK/128, 1), blk, 0, stream>>>(
        fbsum_bf, nullptr, DMODEL, proj_wT, nullptr, DMODEL,
        (float*)d_out, nullptr, nullptr, nullptr, DMODEL, DMODEL,
        proj_b, nullptr, x);
}